// Round 3
// baseline (379.597 us; speedup 1.0000x reference)
//
#include <hip/hip_runtime.h>
#include <math.h>

// B=4, L=32, HP=32, H=64, W=64, D=32, DFFN=64
// 3-kernel structure:
//   k_stats: stats + in_proj + LN1 + r/k/v projections (kv packed float2)
//            + zero-init of the two scalar outputs               [4096 blocks]
//   k_wkv:   WKV scan, 1 channel/lane, all-32-layer kv preloaded [64 blocks x 64]
//   k_merge: x preloaded to regs -> wave-0-only front-end (no block barriers)
//            -> single sync -> mask+merge stream + scalar atomics [4096 blocks]
// ws layout (floats): f 131072 | r 131072 | kv 262144 | wkv 131072  ([l][b][hp][d])

__device__ __forceinline__ float sigf(float v) { return 1.0f / (1.0f + __expf(-v)); }

// ---------------------------------------------------------------------------
// k_stats: per-(b,l,hp) stats over a/b, in_proj -> feat, then LN1 + r/k/v.
// ---------------------------------------------------------------------------
__global__ __launch_bounds__(256) void k_stats(
    const float* __restrict__ x, const float* __restrict__ in_proj_w,
    const float* __restrict__ in_proj_b, const float* __restrict__ layer_emb,
    const float* __restrict__ ln_tm_g, const float* __restrict__ ln_tm_b,
    const float* __restrict__ tm_r, const float* __restrict__ tm_k,
    const float* __restrict__ tm_v,
    float* __restrict__ f_out, float* __restrict__ r_out,
    float* __restrict__ kv_out, float* __restrict__ out)
{
    __shared__ float red[4][9];
    __shared__ float tot[9];
    __shared__ __align__(16) float xn_s[32];
    const int bid = blockIdx.x;
    const int hp = bid & 31, l = (bid >> 5) & 31, bb = bid >> 10;
    const float4* pa = (const float4*)(x + (size_t)(bb * 2048 + l * 32 + hp) * 4096);
    const float4* pb = (const float4*)(x + (size_t)(bb * 2048 + 1024 + l * 32 + hp) * 4096);
    const int t = threadIdx.x;
    const int gidx = ((l * 4 + bb) * 32 + hp) * 32;

    // zero the scalar accumulators consumed by k_merge's atomics
    if (bid == 0 && t == 0) { out[16777216] = 0.f; out[16777217] = 0.f; }

    float sa = 0.f, saa = 0.f, sb = 0.f, sbb = 0.f, sab = 0.f;
    float mna = 3.4e38f, mxa = -3.4e38f, mnb = 3.4e38f, mxb = -3.4e38f;
#pragma unroll
    for (int it = 0; it < 4; ++it) {
        float4 a4 = pa[t + it * 256];
        float4 b4 = pb[t + it * 256];
        sa  += a4.x + a4.y + a4.z + a4.w;
        sb  += b4.x + b4.y + b4.z + b4.w;
        saa += a4.x * a4.x + a4.y * a4.y + a4.z * a4.z + a4.w * a4.w;
        sbb += b4.x * b4.x + b4.y * b4.y + b4.z * b4.z + b4.w * b4.w;
        sab += a4.x * b4.x + a4.y * b4.y + a4.z * b4.z + a4.w * b4.w;
        mna = fminf(mna, fminf(fminf(a4.x, a4.y), fminf(a4.z, a4.w)));
        mxa = fmaxf(mxa, fmaxf(fmaxf(a4.x, a4.y), fmaxf(a4.z, a4.w)));
        mnb = fminf(mnb, fminf(fminf(b4.x, b4.y), fminf(b4.z, b4.w)));
        mxb = fmaxf(mxb, fmaxf(fmaxf(b4.x, b4.y), fmaxf(b4.z, b4.w)));
    }
#pragma unroll
    for (int m = 1; m < 64; m <<= 1) {
        sa  += __shfl_xor(sa, m);
        saa += __shfl_xor(saa, m);
        sb  += __shfl_xor(sb, m);
        sbb += __shfl_xor(sbb, m);
        sab += __shfl_xor(sab, m);
        mna = fminf(mna, __shfl_xor(mna, m));
        mxa = fmaxf(mxa, __shfl_xor(mxa, m));
        mnb = fminf(mnb, __shfl_xor(mnb, m));
        mxb = fmaxf(mxb, __shfl_xor(mxb, m));
    }
    const int lane = t & 63, wv = t >> 6;
    if (lane == 0) {
        red[wv][0] = sa;  red[wv][1] = saa; red[wv][2] = sb;  red[wv][3] = sbb;
        red[wv][4] = sab; red[wv][5] = mna; red[wv][6] = mxa; red[wv][7] = mnb;
        red[wv][8] = mxb;
    }
    __syncthreads();
    if (t == 0) {
#pragma unroll
        for (int q = 0; q < 5; ++q) tot[q] = red[0][q] + red[1][q] + red[2][q] + red[3][q];
        tot[5] = fminf(fminf(red[0][5], red[1][5]), fminf(red[2][5], red[3][5]));
        tot[6] = fmaxf(fmaxf(red[0][6], red[1][6]), fmaxf(red[2][6], red[3][6]));
        tot[7] = fminf(fminf(red[0][7], red[1][7]), fminf(red[2][7], red[3][7]));
        tot[8] = fmaxf(fmaxf(red[0][8], red[1][8]), fmaxf(red[2][8], red[3][8]));
    }
    __syncthreads();
    if (t < 32) {
        const float SA = tot[0], SAA = tot[1], SB = tot[2], SBB = tot[3], SAB = tot[4];
        const float inv_n = 1.f / 4096.f, inv_nm1 = 1.f / 4095.f;
        float st[12];
        st[0] = SA * inv_n;
        st[1] = sqrtf(fmaxf(SAA - SA * SA * inv_n, 0.f) * inv_nm1);
        st[2] = tot[5]; st[3] = tot[6];
        st[4] = SB * inv_n;
        st[5] = sqrtf(fmaxf(SBB - SB * SB * inv_n, 0.f) * inv_nm1);
        st[6] = tot[7]; st[7] = tot[8];
        const float SD = SA - SB, SDD = SAA - 2.f * SAB + SBB;
        st[8]  = SD * inv_n;
        st[9]  = sqrtf(fmaxf(SDD - SD * SD * inv_n, 0.f) * inv_nm1);
        st[10] = sqrtf(fmaxf(SDD, 0.f));
        const float na = fmaxf(sqrtf(SAA), 1e-8f), nb2 = fmaxf(sqrtf(SBB), 1e-8f);
        st[11] = SAB / (na * nb2);
        float fv = in_proj_b[t] + layer_emb[l * 32 + t];
#pragma unroll
        for (int s2 = 0; s2 < 12; ++s2) fv += st[s2] * in_proj_w[t * 12 + s2];
        f_out[gidx + t] = fv;
        // LN1 across the 32 channels (lanes 0..31 of wave 0)
        float s = fv, q = fv * fv;
#pragma unroll
        for (int m = 1; m < 32; m <<= 1) { s += __shfl_xor(s, m, 32); q += __shfl_xor(q, m, 32); }
        const float mu = s * (1.f / 32.f);
        const float var = fmaxf(q * (1.f / 32.f) - mu * mu, 0.f);
        xn_s[t] = (fv - mu) * rsqrtf(var + 1e-5f) * ln_tm_g[t] + ln_tm_b[t];
    }
    __syncthreads();
    // r/k/v projections: threads 0..95, one output dot each; k/v packed float2
    if (t < 96) {
        const int d = t & 31;
        const float* wrow = (t < 32 ? tm_r : (t < 64 ? tm_k : tm_v)) + d * 32;
        const float4* w4 = (const float4*)wrow;
        const float4* x4 = (const float4*)xn_s;
        float a0 = 0.f, a1 = 0.f, a2 = 0.f, a3 = 0.f;
#pragma unroll
        for (int jq = 0; jq < 2; ++jq) {
            float4 w, xv;
            w = w4[jq];     xv = x4[jq];     a0 += w.x*xv.x + w.y*xv.y + w.z*xv.z + w.w*xv.w;
            w = w4[jq + 2]; xv = x4[jq + 2]; a1 += w.x*xv.x + w.y*xv.y + w.z*xv.z + w.w*xv.w;
            w = w4[jq + 4]; xv = x4[jq + 4]; a2 += w.x*xv.x + w.y*xv.y + w.z*xv.z + w.w*xv.w;
            w = w4[jq + 6]; xv = x4[jq + 6]; a3 += w.x*xv.x + w.y*xv.y + w.z*xv.z + w.w*xv.w;
        }
        const float dot = (a0 + a1) + (a2 + a3);
        if (t < 32)      r_out[gidx + d] = sigf(dot);
        else if (t < 64) kv_out[2 * (gidx + d)] = dot;       // k
        else             kv_out[2 * (gidx + d) + 1] = dot;   // v
    }
}

// ---------------------------------------------------------------------------
// k_wkv: one channel per lane; all 32 layers' (k,v) preloaded into registers
// so the 32 L2-latency loads overlap in one burst; then the serial chain.
// ---------------------------------------------------------------------------
__global__ __launch_bounds__(64) void k_wkv(
    const float* __restrict__ kv_in,
    const float* __restrict__ time_decay, const float* __restrict__ time_first,
    float* __restrict__ wkv_out)
{
    const int ch = blockIdx.x * 64 + threadIdx.x;   // (bb*32+hp)*32+d, 4096 total
    const int d = ch & 31;
    const float tf = time_first[d];
    const float wd = __expf(time_decay[d]);
    const float2* kv2 = (const float2*)kv_in;
    float2 kv[32];
#pragma unroll
    for (int l = 0; l < 32; ++l) kv[l] = kv2[l * 4096 + ch];
    float aa = 0.f, bbs = 0.f, pp = -1e30f;
#pragma unroll
    for (int l = 0; l < 32; ++l) {
        const float kc = kv[l].x, vc = kv[l].y;
        const float ww = tf + kc;
        const float p = fmaxf(pp, ww);
        const float e1 = __expf(pp - p), e2 = __expf(ww - p);
        wkv_out[l * 4096 + ch] = (e1 * aa + e2 * vc) / fmaxf(e1 * bbs + e2, 1e-8f);
        const float ww2 = pp - wd;
        const float p2 = fmaxf(ww2, kc);
        const float e1b = __expf(ww2 - p2), e2b = __expf(kc - p2);
        aa = e1b * aa + e2b * vc;
        bbs = e1b * bbs + e2b;
        pp = p2;
    }
}

// ---------------------------------------------------------------------------
// k_merge: preload x to regs, wave-0-only front-end (LDS scratch, intra-wave
// ordering only), ONE __syncthreads, then mask+merge stream + atomics.
// ---------------------------------------------------------------------------
__global__ __launch_bounds__(256) void k_merge(
    const float* __restrict__ x,
    const float* __restrict__ f_in, const float* __restrict__ r_in,
    const float* __restrict__ wkv_in,
    const float* __restrict__ tm_out,
    const float* __restrict__ ln_cm_g, const float* __restrict__ ln_cm_b,
    const float* __restrict__ cm_k, const float* __restrict__ cm_v,
    const float* __restrict__ cm_r,
    const float* __restrict__ gate_w, const float* __restrict__ gate_b,
    const float* __restrict__ row_w, const float* __restrict__ row_b,
    const float* __restrict__ col_w, const float* __restrict__ col_b,
    float* __restrict__ out)
{
    __shared__ __align__(16) float wkv_s[32];
    __shared__ __align__(16) float xn2_s[32];
    __shared__ __align__(16) float kk_s[64];
    __shared__ __align__(16) float fs[32];     // final feats (y2)
    __shared__ float row_s[64], col_s[64];
    __shared__ float gate_sh;
    __shared__ float red2[4];
    const int bid = blockIdx.x;
    const int hp = bid & 31, l = (bid >> 5) & 31, bb = bid >> 10;
    const int t = threadIdx.x;
    const int gidx = ((l * 4 + bb) * 32 + hp) * 32;

    const float4* pa = (const float4*)(x + (size_t)(bb * 2048 + l * 32 + hp) * 4096);
    const float4* pb = (const float4*)(x + (size_t)(bb * 2048 + 1024 + l * 32 + hp) * 4096);
    float4* po = (float4*)(out + (size_t)(bb * 1024 + l * 32 + hp) * 4096);

    // ---- issue all x loads first (front-end latency hides under them) ----
    float4 av[4], bv[4];
#pragma unroll
    for (int it = 0; it < 4; ++it) {
        av[it] = pa[t + it * 256];
        bv[it] = pb[t + it * 256];
    }

    // ---- wave-0-only front-end: no block-wide barriers in here ----
    if (t < 64) {
        float yv = 0.f, y2 = 0.f;
        if (t < 32) {
            wkv_s[t] = wkv_in[gidx + t];
            const float fv = f_in[gidx + t];
            const float rv = r_in[gidx + t];
            // y = f + r * (wkv @ tm_out[t]);  wkv via LDS (same-wave ordering)
            const float4* w4 = (const float4*)(tm_out + t * 32);
            const float4* x4 = (const float4*)wkv_s;
            float a0 = 0.f, a1 = 0.f, a2 = 0.f, a3 = 0.f;
#pragma unroll
            for (int jq = 0; jq < 2; ++jq) {
                float4 w, xv;
                w = w4[jq];     xv = x4[jq];     a0 += w.x*xv.x + w.y*xv.y + w.z*xv.z + w.w*xv.w;
                w = w4[jq + 2]; xv = x4[jq + 2]; a1 += w.x*xv.x + w.y*xv.y + w.z*xv.z + w.w*xv.w;
                w = w4[jq + 4]; xv = x4[jq + 4]; a2 += w.x*xv.x + w.y*xv.y + w.z*xv.z + w.w*xv.w;
                w = w4[jq + 6]; xv = x4[jq + 6]; a3 += w.x*xv.x + w.y*xv.y + w.z*xv.z + w.w*xv.w;
            }
            yv = fv + rv * ((a0 + a1) + (a2 + a3));
            // LN2 across lanes 0..31
            float s = yv, q = yv * yv;
#pragma unroll
            for (int m = 1; m < 32; m <<= 1) { s += __shfl_xor(s, m, 32); q += __shfl_xor(q, m, 32); }
            const float mu = s * (1.f / 32.f);
            const float var = fmaxf(q * (1.f / 32.f) - mu * mu, 0.f);
            xn2_s[t] = (yv - mu) * rsqrtf(var + 1e-5f) * ln_cm_g[t] + ln_cm_b[t];
        }
        {   // kk[e] = relu(xn2 @ cm_k[e])^2  -- all 64 lanes
            const float4* w4 = (const float4*)(cm_k + t * 32);
            const float4* x4 = (const float4*)xn2_s;
            float a0 = 0.f, a1 = 0.f, a2 = 0.f, a3 = 0.f;
#pragma unroll
            for (int jq = 0; jq < 2; ++jq) {
                float4 w, xv;
                w = w4[jq];     xv = x4[jq];     a0 += w.x*xv.x + w.y*xv.y + w.z*xv.z + w.w*xv.w;
                w = w4[jq + 2]; xv = x4[jq + 2]; a1 += w.x*xv.x + w.y*xv.y + w.z*xv.z + w.w*xv.w;
                w = w4[jq + 4]; xv = x4[jq + 4]; a2 += w.x*xv.x + w.y*xv.y + w.z*xv.z + w.w*xv.w;
                w = w4[jq + 6]; xv = x4[jq + 6]; a3 += w.x*xv.x + w.y*xv.y + w.z*xv.z + w.w*xv.w;
            }
            float kk = fmaxf((a0 + a1) + (a2 + a3), 0.f);
            kk_s[t] = kk * kk;
        }
        if (t < 32) {
            // cr[d] = sigmoid(xn2 @ cm_r[d])
            float cr;
            {
                const float4* w4 = (const float4*)(cm_r + t * 32);
                const float4* x4 = (const float4*)xn2_s;
                float a0 = 0.f, a1 = 0.f, a2 = 0.f, a3 = 0.f;
#pragma unroll
                for (int jq = 0; jq < 2; ++jq) {
                    float4 w, xv;
                    w = w4[jq];     xv = x4[jq];     a0 += w.x*xv.x + w.y*xv.y + w.z*xv.z + w.w*xv.w;
                    w = w4[jq + 2]; xv = x4[jq + 2]; a1 += w.x*xv.x + w.y*xv.y + w.z*xv.z + w.w*xv.w;
                    w = w4[jq + 4]; xv = x4[jq + 4]; a2 += w.x*xv.x + w.y*xv.y + w.z*xv.z + w.w*xv.w;
                    w = w4[jq + 6]; xv = x4[jq + 6]; a3 += w.x*xv.x + w.y*xv.y + w.z*xv.z + w.w*xv.w;
                }
                cr = sigf((a0 + a1) + (a2 + a3));
            }
            // y2 = y + cr * (kk @ cm_v[t])
            {
                const float4* w4 = (const float4*)(cm_v + t * 64);
                const float4* x4 = (const float4*)kk_s;
                float a0 = 0.f, a1 = 0.f, a2 = 0.f, a3 = 0.f;
#pragma unroll
                for (int jq = 0; jq < 4; ++jq) {
                    float4 w, xv;
                    w = w4[jq];      xv = x4[jq];      a0 += w.x*xv.x + w.y*xv.y + w.z*xv.z + w.w*xv.w;
                    w = w4[jq + 4];  xv = x4[jq + 4];  a1 += w.x*xv.x + w.y*xv.y + w.z*xv.z + w.w*xv.w;
                    w = w4[jq + 8];  xv = x4[jq + 8];  a2 += w.x*xv.x + w.y*xv.y + w.z*xv.z + w.w*xv.w;
                    w = w4[jq + 12]; xv = x4[jq + 12]; a3 += w.x*xv.x + w.y*xv.y + w.z*xv.z + w.w*xv.w;
                }
                y2 = yv + cr * ((a0 + a1) + (a2 + a3));
            }
            fs[t] = y2;
            // gate = fs . gate_w + gate_b via shuffle reduce (width 32)
            float g = y2 * gate_w[t];
#pragma unroll
            for (int m = 1; m < 32; m <<= 1) g += __shfl_xor(g, m, 32);
            if (t == 0) gate_sh = g + gate_b[0];
        }
        {   // row_s[t] and col_s[t] from fs (all 64 lanes)
            float a0 = row_b[t], a1 = 0.f, a2 = 0.f, a3 = 0.f;
            float c0 = col_b[t], c1 = 0.f, c2 = 0.f, c3 = 0.f;
#pragma unroll
            for (int d2 = 0; d2 < 8; ++d2) {
                const float f0 = fs[d2], f1 = fs[d2 + 8], f2 = fs[d2 + 16], f3 = fs[d2 + 24];
                a0 += f0 * row_w[t * 32 + d2];
                a1 += f1 * row_w[t * 32 + d2 + 8];
                a2 += f2 * row_w[t * 32 + d2 + 16];
                a3 += f3 * row_w[t * 32 + d2 + 24];
                c0 += f0 * col_w[t * 32 + d2];
                c1 += f1 * col_w[t * 32 + d2 + 8];
                c2 += f2 * col_w[t * 32 + d2 + 16];
                c3 += f3 * col_w[t * 32 + d2 + 24];
            }
            row_s[t] = (a0 + a1) + (a2 + a3);
            col_s[t] = (c0 + c1) + (c2 + c3);
        }
    }
    __syncthreads();   // the ONLY pre-stream barrier

    const float gate = gate_sh;
    float msum = 0.f;
#pragma unroll
    for (int it = 0; it < 4; ++it) {
        const int i = t + it * 256;
        const float4 a4 = av[it];
        const float4 b4 = bv[it];
        const int h = i >> 4, w0 = (i & 15) * 4;
        const float gr = gate + row_s[h];
        const float m0 = sigf(gr + col_s[w0 + 0]);
        const float m1 = sigf(gr + col_s[w0 + 1]);
        const float m2 = sigf(gr + col_s[w0 + 2]);
        const float m3 = sigf(gr + col_s[w0 + 3]);
        float4 o;
        o.x = b4.x + m0 * (a4.x - b4.x);
        o.y = b4.y + m1 * (a4.y - b4.y);
        o.z = b4.z + m2 * (a4.z - b4.z);
        o.w = b4.w + m3 * (a4.w - b4.w);
        po[i] = o;
        msum += m0 + m1 + m2 + m3;
    }
#pragma unroll
    for (int m = 1; m < 64; m <<= 1) msum += __shfl_xor(msum, m);
    if ((t & 63) == 0) red2[t >> 6] = msum;
    __syncthreads();
    if (t == 0) {
        atomicAdd(out + 16777217, (red2[0] + red2[1] + red2[2] + red2[3]) * (1.f / 16777216.f));
        atomicAdd(out + 16777216, sigf(gate) * (1.f / 4096.f));
    }
}

extern "C" void kernel_launch(void* const* d_in, const int* in_sizes, int n_in,
                              void* d_out, int out_size, void* d_ws, size_t ws_size,
                              hipStream_t stream) {
    const float* x          = (const float*)d_in[0];
    const float* in_proj_w  = (const float*)d_in[1];
    const float* in_proj_b  = (const float*)d_in[2];
    const float* layer_emb  = (const float*)d_in[3];
    const float* time_decay = (const float*)d_in[4];
    const float* time_first = (const float*)d_in[5];
    const float* ln_tm_g    = (const float*)d_in[6];
    const float* ln_tm_b    = (const float*)d_in[7];
    const float* tm_r       = (const float*)d_in[8];
    const float* tm_k       = (const float*)d_in[9];
    const float* tm_v       = (const float*)d_in[10];
    const float* tm_out     = (const float*)d_in[11];
    const float* ln_cm_g    = (const float*)d_in[12];
    const float* ln_cm_b    = (const float*)d_in[13];
    const float* cm_k       = (const float*)d_in[14];
    const float* cm_v       = (const float*)d_in[15];
    const float* cm_r       = (const float*)d_in[16];
    const float* gate_w     = (const float*)d_in[17];
    const float* gate_b     = (const float*)d_in[18];
    const float* row_w      = (const float*)d_in[19];
    const float* row_b      = (const float*)d_in[20];
    const float* col_w      = (const float*)d_in[21];
    const float* col_b      = (const float*)d_in[22];
    float* out = (float*)d_out;

    float* wsf    = (float*)d_ws;
    float* f_ws   = wsf;               // 131072  [l][b][hp][d]
    float* r_ws   = wsf + 131072;      // 131072
    float* kv_ws  = wsf + 262144;      // 262144  [l][b][hp][d] x {k,v} packed
    float* wkv_ws = wsf + 524288;      // 131072

    k_stats<<<dim3(4096), dim3(256), 0, stream>>>(
        x, in_proj_w, in_proj_b, layer_emb, ln_tm_g, ln_tm_b,
        tm_r, tm_k, tm_v, f_ws, r_ws, kv_ws, out);
    k_wkv<<<dim3(64), dim3(64), 0, stream>>>(
        kv_ws, time_decay, time_first, wkv_ws);
    k_merge<<<dim3(4096), dim3(256), 0, stream>>>(
        x, f_ws, r_ws, wkv_ws, tm_out, ln_cm_g, ln_cm_b, cm_k, cm_v, cm_r,
        gate_w, gate_b, row_w, row_b, col_w, col_b, out);
}

// Round 4
// 307.444 us; speedup vs baseline: 1.2347x; 1.2347x over previous
//
#include <hip/hip_runtime.h>
#include <math.h>

// B=4, L=32, HP=32, H=64, W=64, D=32, DFFN=64
// 4-kernel structure (NO same-address atomics — they serialized at ~16ns/op
// across XCD L2s and put a 133us floor under k_merge in R2/R3):
//   k_stats: stats + in_proj + LN1 + r/k/v projections (kv packed float2)
//   k_wkv:   WKV scan, 1 channel/lane, all-32-layer kv preloaded [64 blocks x 64]
//   k_merge: x preloaded to regs -> wave-0-only front-end (no block barriers)
//            -> single sync -> mask+merge stream + per-block partial stores
//   k_final: reduce 4096 partials -> 2 scalars [1 block]
// ws layout (floats): f 131072 | r 131072 | kv 262144 | wkv 131072
//                     | gpart 4096 | mpart 4096        ([l][b][hp][d])

__device__ __forceinline__ float sigf(float v) { return 1.0f / (1.0f + __expf(-v)); }

// ---------------------------------------------------------------------------
// k_stats: per-(b,l,hp) stats over a/b, in_proj -> feat, then LN1 + r/k/v.
// ---------------------------------------------------------------------------
__global__ __launch_bounds__(256) void k_stats(
    const float* __restrict__ x, const float* __restrict__ in_proj_w,
    const float* __restrict__ in_proj_b, const float* __restrict__ layer_emb,
    const float* __restrict__ ln_tm_g, const float* __restrict__ ln_tm_b,
    const float* __restrict__ tm_r, const float* __restrict__ tm_k,
    const float* __restrict__ tm_v,
    float* __restrict__ f_out, float* __restrict__ r_out,
    float* __restrict__ kv_out)
{
    __shared__ float red[4][9];
    __shared__ float tot[9];
    __shared__ __align__(16) float xn_s[32];
    const int bid = blockIdx.x;
    const int hp = bid & 31, l = (bid >> 5) & 31, bb = bid >> 10;
    const float4* pa = (const float4*)(x + (size_t)(bb * 2048 + l * 32 + hp) * 4096);
    const float4* pb = (const float4*)(x + (size_t)(bb * 2048 + 1024 + l * 32 + hp) * 4096);
    const int t = threadIdx.x;
    const int gidx = ((l * 4 + bb) * 32 + hp) * 32;

    float sa = 0.f, saa = 0.f, sb = 0.f, sbb = 0.f, sab = 0.f;
    float mna = 3.4e38f, mxa = -3.4e38f, mnb = 3.4e38f, mxb = -3.4e38f;
#pragma unroll
    for (int it = 0; it < 4; ++it) {
        float4 a4 = pa[t + it * 256];
        float4 b4 = pb[t + it * 256];
        sa  += a4.x + a4.y + a4.z + a4.w;
        sb  += b4.x + b4.y + b4.z + b4.w;
        saa += a4.x * a4.x + a4.y * a4.y + a4.z * a4.z + a4.w * a4.w;
        sbb += b4.x * b4.x + b4.y * b4.y + b4.z * b4.z + b4.w * b4.w;
        sab += a4.x * b4.x + a4.y * b4.y + a4.z * b4.z + a4.w * b4.w;
        mna = fminf(mna, fminf(fminf(a4.x, a4.y), fminf(a4.z, a4.w)));
        mxa = fmaxf(mxa, fmaxf(fmaxf(a4.x, a4.y), fmaxf(a4.z, a4.w)));
        mnb = fminf(mnb, fminf(fminf(b4.x, b4.y), fminf(b4.z, b4.w)));
        mxb = fmaxf(mxb, fmaxf(fmaxf(b4.x, b4.y), fmaxf(b4.z, b4.w)));
    }
#pragma unroll
    for (int m = 1; m < 64; m <<= 1) {
        sa  += __shfl_xor(sa, m);
        saa += __shfl_xor(saa, m);
        sb  += __shfl_xor(sb, m);
        sbb += __shfl_xor(sbb, m);
        sab += __shfl_xor(sab, m);
        mna = fminf(mna, __shfl_xor(mna, m));
        mxa = fmaxf(mxa, __shfl_xor(mxa, m));
        mnb = fminf(mnb, __shfl_xor(mnb, m));
        mxb = fmaxf(mxb, __shfl_xor(mxb, m));
    }
    const int lane = t & 63, wv = t >> 6;
    if (lane == 0) {
        red[wv][0] = sa;  red[wv][1] = saa; red[wv][2] = sb;  red[wv][3] = sbb;
        red[wv][4] = sab; red[wv][5] = mna; red[wv][6] = mxa; red[wv][7] = mnb;
        red[wv][8] = mxb;
    }
    __syncthreads();
    if (t == 0) {
#pragma unroll
        for (int q = 0; q < 5; ++q) tot[q] = red[0][q] + red[1][q] + red[2][q] + red[3][q];
        tot[5] = fminf(fminf(red[0][5], red[1][5]), fminf(red[2][5], red[3][5]));
        tot[6] = fmaxf(fmaxf(red[0][6], red[1][6]), fmaxf(red[2][6], red[3][6]));
        tot[7] = fminf(fminf(red[0][7], red[1][7]), fminf(red[2][7], red[3][7]));
        tot[8] = fmaxf(fmaxf(red[0][8], red[1][8]), fmaxf(red[2][8], red[3][8]));
    }
    __syncthreads();
    if (t < 32) {
        const float SA = tot[0], SAA = tot[1], SB = tot[2], SBB = tot[3], SAB = tot[4];
        const float inv_n = 1.f / 4096.f, inv_nm1 = 1.f / 4095.f;
        float st[12];
        st[0] = SA * inv_n;
        st[1] = sqrtf(fmaxf(SAA - SA * SA * inv_n, 0.f) * inv_nm1);
        st[2] = tot[5]; st[3] = tot[6];
        st[4] = SB * inv_n;
        st[5] = sqrtf(fmaxf(SBB - SB * SB * inv_n, 0.f) * inv_nm1);
        st[6] = tot[7]; st[7] = tot[8];
        const float SD = SA - SB, SDD = SAA - 2.f * SAB + SBB;
        st[8]  = SD * inv_n;
        st[9]  = sqrtf(fmaxf(SDD - SD * SD * inv_n, 0.f) * inv_nm1);
        st[10] = sqrtf(fmaxf(SDD, 0.f));
        const float na = fmaxf(sqrtf(SAA), 1e-8f), nb2 = fmaxf(sqrtf(SBB), 1e-8f);
        st[11] = SAB / (na * nb2);
        float fv = in_proj_b[t] + layer_emb[l * 32 + t];
#pragma unroll
        for (int s2 = 0; s2 < 12; ++s2) fv += st[s2] * in_proj_w[t * 12 + s2];
        f_out[gidx + t] = fv;
        // LN1 across the 32 channels (lanes 0..31 of wave 0)
        float s = fv, q = fv * fv;
#pragma unroll
        for (int m = 1; m < 32; m <<= 1) { s += __shfl_xor(s, m, 32); q += __shfl_xor(q, m, 32); }
        const float mu = s * (1.f / 32.f);
        const float var = fmaxf(q * (1.f / 32.f) - mu * mu, 0.f);
        xn_s[t] = (fv - mu) * rsqrtf(var + 1e-5f) * ln_tm_g[t] + ln_tm_b[t];
    }
    __syncthreads();
    // r/k/v projections: threads 0..95, one output dot each; k/v packed float2
    if (t < 96) {
        const int d = t & 31;
        const float* wrow = (t < 32 ? tm_r : (t < 64 ? tm_k : tm_v)) + d * 32;
        const float4* w4 = (const float4*)wrow;
        const float4* x4 = (const float4*)xn_s;
        float a0 = 0.f, a1 = 0.f, a2 = 0.f, a3 = 0.f;
#pragma unroll
        for (int jq = 0; jq < 2; ++jq) {
            float4 w, xv;
            w = w4[jq];     xv = x4[jq];     a0 += w.x*xv.x + w.y*xv.y + w.z*xv.z + w.w*xv.w;
            w = w4[jq + 2]; xv = x4[jq + 2]; a1 += w.x*xv.x + w.y*xv.y + w.z*xv.z + w.w*xv.w;
            w = w4[jq + 4]; xv = x4[jq + 4]; a2 += w.x*xv.x + w.y*xv.y + w.z*xv.z + w.w*xv.w;
            w = w4[jq + 6]; xv = x4[jq + 6]; a3 += w.x*xv.x + w.y*xv.y + w.z*xv.z + w.w*xv.w;
        }
        const float dot = (a0 + a1) + (a2 + a3);
        if (t < 32)      r_out[gidx + d] = sigf(dot);
        else if (t < 64) kv_out[2 * (gidx + d)] = dot;       // k
        else             kv_out[2 * (gidx + d) + 1] = dot;   // v
    }
}

// ---------------------------------------------------------------------------
// k_wkv: one channel per lane; all 32 layers' (k,v) preloaded into registers
// so the 32 L2-latency loads overlap in one burst; then the serial chain.
// ---------------------------------------------------------------------------
__global__ __launch_bounds__(64) void k_wkv(
    const float* __restrict__ kv_in,
    const float* __restrict__ time_decay, const float* __restrict__ time_first,
    float* __restrict__ wkv_out)
{
    const int ch = blockIdx.x * 64 + threadIdx.x;   // (bb*32+hp)*32+d, 4096 total
    const int d = ch & 31;
    const float tf = time_first[d];
    const float wd = __expf(time_decay[d]);
    const float2* kv2 = (const float2*)kv_in;
    float2 kv[32];
#pragma unroll
    for (int l = 0; l < 32; ++l) kv[l] = kv2[l * 4096 + ch];
    float aa = 0.f, bbs = 0.f, pp = -1e30f;
#pragma unroll
    for (int l = 0; l < 32; ++l) {
        const float kc = kv[l].x, vc = kv[l].y;
        const float ww = tf + kc;
        const float p = fmaxf(pp, ww);
        const float e1 = __expf(pp - p), e2 = __expf(ww - p);
        wkv_out[l * 4096 + ch] = (e1 * aa + e2 * vc) / fmaxf(e1 * bbs + e2, 1e-8f);
        const float ww2 = pp - wd;
        const float p2 = fmaxf(ww2, kc);
        const float e1b = __expf(ww2 - p2), e2b = __expf(kc - p2);
        aa = e1b * aa + e2b * vc;
        bbs = e1b * bbs + e2b;
        pp = p2;
    }
}

// ---------------------------------------------------------------------------
// k_merge: preload x to regs, wave-0-only front-end (LDS scratch, intra-wave
// ordering only), ONE __syncthreads, then mask+merge stream; per-block
// partial sums stored contention-free (NOT atomics).
// ---------------------------------------------------------------------------
__global__ __launch_bounds__(256) void k_merge(
    const float* __restrict__ x,
    const float* __restrict__ f_in, const float* __restrict__ r_in,
    const float* __restrict__ wkv_in,
    const float* __restrict__ tm_out,
    const float* __restrict__ ln_cm_g, const float* __restrict__ ln_cm_b,
    const float* __restrict__ cm_k, const float* __restrict__ cm_v,
    const float* __restrict__ cm_r,
    const float* __restrict__ gate_w, const float* __restrict__ gate_b,
    const float* __restrict__ row_w, const float* __restrict__ row_b,
    const float* __restrict__ col_w, const float* __restrict__ col_b,
    float* __restrict__ out, float* __restrict__ gpart, float* __restrict__ mpart)
{
    __shared__ __align__(16) float wkv_s[32];
    __shared__ __align__(16) float xn2_s[32];
    __shared__ __align__(16) float kk_s[64];
    __shared__ __align__(16) float fs[32];     // final feats (y2)
    __shared__ float row_s[64], col_s[64];
    __shared__ float gate_sh;
    __shared__ float red2[4];
    const int bid = blockIdx.x;
    const int hp = bid & 31, l = (bid >> 5) & 31, bb = bid >> 10;
    const int t = threadIdx.x;
    const int gidx = ((l * 4 + bb) * 32 + hp) * 32;

    const float4* pa = (const float4*)(x + (size_t)(bb * 2048 + l * 32 + hp) * 4096);
    const float4* pb = (const float4*)(x + (size_t)(bb * 2048 + 1024 + l * 32 + hp) * 4096);
    float4* po = (float4*)(out + (size_t)(bb * 1024 + l * 32 + hp) * 4096);

    // ---- issue all x loads first (front-end latency hides under them) ----
    float4 av[4], bv[4];
#pragma unroll
    for (int it = 0; it < 4; ++it) {
        av[it] = pa[t + it * 256];
        bv[it] = pb[t + it * 256];
    }

    // ---- wave-0-only front-end: no block-wide barriers in here ----
    if (t < 64) {
        float yv = 0.f, y2 = 0.f;
        if (t < 32) {
            wkv_s[t] = wkv_in[gidx + t];
            const float fv = f_in[gidx + t];
            const float rv = r_in[gidx + t];
            // y = f + r * (wkv @ tm_out[t]);  wkv via LDS (same-wave ordering)
            const float4* w4 = (const float4*)(tm_out + t * 32);
            const float4* x4 = (const float4*)wkv_s;
            float a0 = 0.f, a1 = 0.f, a2 = 0.f, a3 = 0.f;
#pragma unroll
            for (int jq = 0; jq < 2; ++jq) {
                float4 w, xv;
                w = w4[jq];     xv = x4[jq];     a0 += w.x*xv.x + w.y*xv.y + w.z*xv.z + w.w*xv.w;
                w = w4[jq + 2]; xv = x4[jq + 2]; a1 += w.x*xv.x + w.y*xv.y + w.z*xv.z + w.w*xv.w;
                w = w4[jq + 4]; xv = x4[jq + 4]; a2 += w.x*xv.x + w.y*xv.y + w.z*xv.z + w.w*xv.w;
                w = w4[jq + 6]; xv = x4[jq + 6]; a3 += w.x*xv.x + w.y*xv.y + w.z*xv.z + w.w*xv.w;
            }
            yv = fv + rv * ((a0 + a1) + (a2 + a3));
            // LN2 across lanes 0..31
            float s = yv, q = yv * yv;
#pragma unroll
            for (int m = 1; m < 32; m <<= 1) { s += __shfl_xor(s, m, 32); q += __shfl_xor(q, m, 32); }
            const float mu = s * (1.f / 32.f);
            const float var = fmaxf(q * (1.f / 32.f) - mu * mu, 0.f);
            xn2_s[t] = (yv - mu) * rsqrtf(var + 1e-5f) * ln_cm_g[t] + ln_cm_b[t];
        }
        {   // kk[e] = relu(xn2 @ cm_k[e])^2  -- all 64 lanes
            const float4* w4 = (const float4*)(cm_k + t * 32);
            const float4* x4 = (const float4*)xn2_s;
            float a0 = 0.f, a1 = 0.f, a2 = 0.f, a3 = 0.f;
#pragma unroll
            for (int jq = 0; jq < 2; ++jq) {
                float4 w, xv;
                w = w4[jq];     xv = x4[jq];     a0 += w.x*xv.x + w.y*xv.y + w.z*xv.z + w.w*xv.w;
                w = w4[jq + 2]; xv = x4[jq + 2]; a1 += w.x*xv.x + w.y*xv.y + w.z*xv.z + w.w*xv.w;
                w = w4[jq + 4]; xv = x4[jq + 4]; a2 += w.x*xv.x + w.y*xv.y + w.z*xv.z + w.w*xv.w;
                w = w4[jq + 6]; xv = x4[jq + 6]; a3 += w.x*xv.x + w.y*xv.y + w.z*xv.z + w.w*xv.w;
            }
            float kk = fmaxf((a0 + a1) + (a2 + a3), 0.f);
            kk_s[t] = kk * kk;
        }
        if (t < 32) {
            // cr[d] = sigmoid(xn2 @ cm_r[d])
            float cr;
            {
                const float4* w4 = (const float4*)(cm_r + t * 32);
                const float4* x4 = (const float4*)xn2_s;
                float a0 = 0.f, a1 = 0.f, a2 = 0.f, a3 = 0.f;
#pragma unroll
                for (int jq = 0; jq < 2; ++jq) {
                    float4 w, xv;
                    w = w4[jq];     xv = x4[jq];     a0 += w.x*xv.x + w.y*xv.y + w.z*xv.z + w.w*xv.w;
                    w = w4[jq + 2]; xv = x4[jq + 2]; a1 += w.x*xv.x + w.y*xv.y + w.z*xv.z + w.w*xv.w;
                    w = w4[jq + 4]; xv = x4[jq + 4]; a2 += w.x*xv.x + w.y*xv.y + w.z*xv.z + w.w*xv.w;
                    w = w4[jq + 6]; xv = x4[jq + 6]; a3 += w.x*xv.x + w.y*xv.y + w.z*xv.z + w.w*xv.w;
                }
                cr = sigf((a0 + a1) + (a2 + a3));
            }
            // y2 = y + cr * (kk @ cm_v[t])
            {
                const float4* w4 = (const float4*)(cm_v + t * 64);
                const float4* x4 = (const float4*)kk_s;
                float a0 = 0.f, a1 = 0.f, a2 = 0.f, a3 = 0.f;
#pragma unroll
                for (int jq = 0; jq < 4; ++jq) {
                    float4 w, xv;
                    w = w4[jq];      xv = x4[jq];      a0 += w.x*xv.x + w.y*xv.y + w.z*xv.z + w.w*xv.w;
                    w = w4[jq + 4];  xv = x4[jq + 4];  a1 += w.x*xv.x + w.y*xv.y + w.z*xv.z + w.w*xv.w;
                    w = w4[jq + 8];  xv = x4[jq + 8];  a2 += w.x*xv.x + w.y*xv.y + w.z*xv.z + w.w*xv.w;
                    w = w4[jq + 12]; xv = x4[jq + 12]; a3 += w.x*xv.x + w.y*xv.y + w.z*xv.z + w.w*xv.w;
                }
                y2 = yv + cr * ((a0 + a1) + (a2 + a3));
            }
            fs[t] = y2;
            // gate = fs . gate_w + gate_b via shuffle reduce (width 32)
            float g = y2 * gate_w[t];
#pragma unroll
            for (int m = 1; m < 32; m <<= 1) g += __shfl_xor(g, m, 32);
            if (t == 0) gate_sh = g + gate_b[0];
        }
        {   // row_s[t] and col_s[t] from fs (all 64 lanes)
            float a0 = row_b[t], a1 = 0.f, a2 = 0.f, a3 = 0.f;
            float c0 = col_b[t], c1 = 0.f, c2 = 0.f, c3 = 0.f;
#pragma unroll
            for (int d2 = 0; d2 < 8; ++d2) {
                const float f0 = fs[d2], f1 = fs[d2 + 8], f2 = fs[d2 + 16], f3 = fs[d2 + 24];
                a0 += f0 * row_w[t * 32 + d2];
                a1 += f1 * row_w[t * 32 + d2 + 8];
                a2 += f2 * row_w[t * 32 + d2 + 16];
                a3 += f3 * row_w[t * 32 + d2 + 24];
                c0 += f0 * col_w[t * 32 + d2];
                c1 += f1 * col_w[t * 32 + d2 + 8];
                c2 += f2 * col_w[t * 32 + d2 + 16];
                c3 += f3 * col_w[t * 32 + d2 + 24];
            }
            row_s[t] = (a0 + a1) + (a2 + a3);
            col_s[t] = (c0 + c1) + (c2 + c3);
        }
    }
    __syncthreads();   // the ONLY pre-stream barrier

    const float gate = gate_sh;
    float msum = 0.f;
#pragma unroll
    for (int it = 0; it < 4; ++it) {
        const int i = t + it * 256;
        const float4 a4 = av[it];
        const float4 b4 = bv[it];
        const int h = i >> 4, w0 = (i & 15) * 4;
        const float gr = gate + row_s[h];
        const float m0 = sigf(gr + col_s[w0 + 0]);
        const float m1 = sigf(gr + col_s[w0 + 1]);
        const float m2 = sigf(gr + col_s[w0 + 2]);
        const float m3 = sigf(gr + col_s[w0 + 3]);
        float4 o;
        o.x = b4.x + m0 * (a4.x - b4.x);
        o.y = b4.y + m1 * (a4.y - b4.y);
        o.z = b4.z + m2 * (a4.z - b4.z);
        o.w = b4.w + m3 * (a4.w - b4.w);
        po[i] = o;
        msum += m0 + m1 + m2 + m3;
    }
#pragma unroll
    for (int m = 1; m < 64; m <<= 1) msum += __shfl_xor(msum, m);
    if ((t & 63) == 0) red2[t >> 6] = msum;
    __syncthreads();
    if (t == 0) {
        mpart[bid] = red2[0] + red2[1] + red2[2] + red2[3];
        gpart[bid] = sigf(gate);
    }
}

// ---------------------------------------------------------------------------
// k_final: reduce 4096 per-block partials into the two scalar outputs.
// ---------------------------------------------------------------------------
__global__ __launch_bounds__(256) void k_final(
    const float* __restrict__ gpart, const float* __restrict__ mpart,
    float* __restrict__ out)
{
    __shared__ float rg[4], rm[4];
    const int t = threadIdx.x;
    float gs = 0.f, ms = 0.f;
    for (int i = t; i < 4096; i += 256) { gs += gpart[i]; ms += mpart[i]; }
#pragma unroll
    for (int m = 1; m < 64; m <<= 1) { gs += __shfl_xor(gs, m); ms += __shfl_xor(ms, m); }
    if ((t & 63) == 0) { rg[t >> 6] = gs; rm[t >> 6] = ms; }
    __syncthreads();
    if (t == 0) {
        out[16777216] = (rg[0] + rg[1] + rg[2] + rg[3]) * (1.f / 4096.f);
        out[16777217] = (rm[0] + rm[1] + rm[2] + rm[3]) * (1.f / 16777216.f);
    }
}

extern "C" void kernel_launch(void* const* d_in, const int* in_sizes, int n_in,
                              void* d_out, int out_size, void* d_ws, size_t ws_size,
                              hipStream_t stream) {
    const float* x          = (const float*)d_in[0];
    const float* in_proj_w  = (const float*)d_in[1];
    const float* in_proj_b  = (const float*)d_in[2];
    const float* layer_emb  = (const float*)d_in[3];
    const float* time_decay = (const float*)d_in[4];
    const float* time_first = (const float*)d_in[5];
    const float* ln_tm_g    = (const float*)d_in[6];
    const float* ln_tm_b    = (const float*)d_in[7];
    const float* tm_r       = (const float*)d_in[8];
    const float* tm_k       = (const float*)d_in[9];
    const float* tm_v       = (const float*)d_in[10];
    const float* tm_out     = (const float*)d_in[11];
    const float* ln_cm_g    = (const float*)d_in[12];
    const float* ln_cm_b    = (const float*)d_in[13];
    const float* cm_k       = (const float*)d_in[14];
    const float* cm_v       = (const float*)d_in[15];
    const float* cm_r       = (const float*)d_in[16];
    const float* gate_w     = (const float*)d_in[17];
    const float* gate_b     = (const float*)d_in[18];
    const float* row_w      = (const float*)d_in[19];
    const float* row_b      = (const float*)d_in[20];
    const float* col_w      = (const float*)d_in[21];
    const float* col_b      = (const float*)d_in[22];
    float* out = (float*)d_out;

    float* wsf    = (float*)d_ws;
    float* f_ws   = wsf;               // 131072  [l][b][hp][d]
    float* r_ws   = wsf + 131072;      // 131072
    float* kv_ws  = wsf + 262144;      // 262144  [l][b][hp][d] x {k,v} packed
    float* wkv_ws = wsf + 524288;      // 131072
    float* gpart  = wsf + 655360;      // 4096
    float* mpart  = wsf + 659456;      // 4096

    k_stats<<<dim3(4096), dim3(256), 0, stream>>>(
        x, in_proj_w, in_proj_b, layer_emb, ln_tm_g, ln_tm_b,
        tm_r, tm_k, tm_v, f_ws, r_ws, kv_ws);
    k_wkv<<<dim3(64), dim3(64), 0, stream>>>(
        kv_ws, time_decay, time_first, wkv_ws);
    k_merge<<<dim3(4096), dim3(256), 0, stream>>>(
        x, f_ws, r_ws, wkv_ws, tm_out, ln_cm_g, ln_cm_b, cm_k, cm_v, cm_r,
        gate_w, gate_b, row_w, row_b, col_w, col_b, out, gpart, mpart);
    k_final<<<dim3(1), dim3(256), 0, stream>>>(gpart, mpart, out);
}

// Round 6
// 300.852 us; speedup vs baseline: 1.2617x; 1.0219x over previous
//
#include <hip/hip_runtime.h>
#include <math.h>

// B=4, L=32, HP=32, H=64, W=64, D=32, DFFN=64
// 4-kernel structure (NO same-address atomics: R2/R3 showed they impose a
// ~133us cross-XCD serialization floor; NO nontemporal stores: correlated
// with container failures in R1/R5):
//   k_stats: stats + in_proj + LN1 + r/k/v projections; 1 barrier, wave-0 tail
//   k_wkv:   WKV scan, 1 channel/lane, all-32-layer kv preloaded [64 x 64]
//   k_merge: wave-0-only front-end (1 barrier), streaming mask+merge,
//            per-block partial stores
//   k_final: reduce 4096 partials -> 2 scalars [1 block]
// ws layout (floats): f 131072 | r 131072 | kv 262144 | wkv 131072
//                     | gpart 4096 | mpart 4096        ([l][b][hp][d])

__device__ __forceinline__ float sigf(float v) { return 1.0f / (1.0f + __expf(-v)); }

// ---------------------------------------------------------------------------
// k_stats: per-(b,l,hp) stats over a/b, in_proj -> feat, then LN1 + r/k/v.
// One __syncthreads total; all post-reduce work on wave 0 (intra-wave LDS
// ordering via lgkmcnt, no further barriers).
// ---------------------------------------------------------------------------
__global__ __launch_bounds__(256, 4) void k_stats(
    const float* __restrict__ x, const float* __restrict__ in_proj_w,
    const float* __restrict__ in_proj_b, const float* __restrict__ layer_emb,
    const float* __restrict__ ln_tm_g, const float* __restrict__ ln_tm_b,
    const float* __restrict__ tm_r, const float* __restrict__ tm_k,
    const float* __restrict__ tm_v,
    float* __restrict__ f_out, float* __restrict__ r_out,
    float* __restrict__ kv_out)
{
    __shared__ float red[4][9];
    __shared__ __align__(16) float xn_s[32];
    const int bid = blockIdx.x;
    const int hp = bid & 31, l = (bid >> 5) & 31, bb = bid >> 10;
    const float4* pa = (const float4*)(x + (size_t)(bb * 2048 + l * 32 + hp) * 4096);
    const float4* pb = (const float4*)(x + (size_t)(bb * 2048 + 1024 + l * 32 + hp) * 4096);
    const int t = threadIdx.x;
    const int gidx = ((l * 4 + bb) * 32 + hp) * 32;

    float sa = 0.f, saa = 0.f, sb = 0.f, sbb = 0.f, sab = 0.f;
    float mna = 3.4e38f, mxa = -3.4e38f, mnb = 3.4e38f, mxb = -3.4e38f;
#pragma unroll
    for (int it = 0; it < 4; ++it) {
        float4 a4 = pa[t + it * 256];
        float4 b4 = pb[t + it * 256];
        sa  += a4.x + a4.y + a4.z + a4.w;
        sb  += b4.x + b4.y + b4.z + b4.w;
        saa += a4.x * a4.x + a4.y * a4.y + a4.z * a4.z + a4.w * a4.w;
        sbb += b4.x * b4.x + b4.y * b4.y + b4.z * b4.z + b4.w * b4.w;
        sab += a4.x * b4.x + a4.y * b4.y + a4.z * b4.z + a4.w * b4.w;
        mna = fminf(mna, fminf(fminf(a4.x, a4.y), fminf(a4.z, a4.w)));
        mxa = fmaxf(mxa, fmaxf(fmaxf(a4.x, a4.y), fmaxf(a4.z, a4.w)));
        mnb = fminf(mnb, fminf(fminf(b4.x, b4.y), fminf(b4.z, b4.w)));
        mxb = fmaxf(mxb, fmaxf(fmaxf(b4.x, b4.y), fmaxf(b4.z, b4.w)));
    }
#pragma unroll
    for (int m = 1; m < 64; m <<= 1) {
        sa  += __shfl_xor(sa, m);
        saa += __shfl_xor(saa, m);
        sb  += __shfl_xor(sb, m);
        sbb += __shfl_xor(sbb, m);
        sab += __shfl_xor(sab, m);
        mna = fminf(mna, __shfl_xor(mna, m));
        mxa = fmaxf(mxa, __shfl_xor(mxa, m));
        mnb = fminf(mnb, __shfl_xor(mnb, m));
        mxb = fmaxf(mxb, __shfl_xor(mxb, m));
    }
    const int lane = t & 63, wv = t >> 6;
    if (lane == 0) {
        red[wv][0] = sa;  red[wv][1] = saa; red[wv][2] = sb;  red[wv][3] = sbb;
        red[wv][4] = sab; red[wv][5] = mna; red[wv][6] = mxa; red[wv][7] = mnb;
        red[wv][8] = mxb;
    }
    __syncthreads();   // the ONLY barrier
    if (t < 64) {
        if (t < 32) {
            // per-lane totals from red[][]: LDS broadcasts, no extra barrier
            const float SA  = red[0][0] + red[1][0] + red[2][0] + red[3][0];
            const float SAA = red[0][1] + red[1][1] + red[2][1] + red[3][1];
            const float SB  = red[0][2] + red[1][2] + red[2][2] + red[3][2];
            const float SBB = red[0][3] + red[1][3] + red[2][3] + red[3][3];
            const float SAB = red[0][4] + red[1][4] + red[2][4] + red[3][4];
            const float MNA = fminf(fminf(red[0][5], red[1][5]), fminf(red[2][5], red[3][5]));
            const float MXA = fmaxf(fmaxf(red[0][6], red[1][6]), fmaxf(red[2][6], red[3][6]));
            const float MNB = fminf(fminf(red[0][7], red[1][7]), fminf(red[2][7], red[3][7]));
            const float MXB = fmaxf(fmaxf(red[0][8], red[1][8]), fmaxf(red[2][8], red[3][8]));
            const float inv_n = 1.f / 4096.f, inv_nm1 = 1.f / 4095.f;
            float st[12];
            st[0] = SA * inv_n;
            st[1] = sqrtf(fmaxf(SAA - SA * SA * inv_n, 0.f) * inv_nm1);
            st[2] = MNA; st[3] = MXA;
            st[4] = SB * inv_n;
            st[5] = sqrtf(fmaxf(SBB - SB * SB * inv_n, 0.f) * inv_nm1);
            st[6] = MNB; st[7] = MXB;
            const float SD = SA - SB, SDD = SAA - 2.f * SAB + SBB;
            st[8]  = SD * inv_n;
            st[9]  = sqrtf(fmaxf(SDD - SD * SD * inv_n, 0.f) * inv_nm1);
            st[10] = sqrtf(fmaxf(SDD, 0.f));
            const float na = fmaxf(sqrtf(SAA), 1e-8f), nb2 = fmaxf(sqrtf(SBB), 1e-8f);
            st[11] = SAB / (na * nb2);
            float fv = in_proj_b[t] + layer_emb[l * 32 + t];
#pragma unroll
            for (int s2 = 0; s2 < 12; ++s2) fv += st[s2] * in_proj_w[t * 12 + s2];
            f_out[gidx + t] = fv;
            // LN1 across lanes 0..31
            float s = fv, q = fv * fv;
#pragma unroll
            for (int m = 1; m < 32; m <<= 1) { s += __shfl_xor(s, m, 32); q += __shfl_xor(q, m, 32); }
            const float mu = s * (1.f / 32.f);
            const float var = fmaxf(q * (1.f / 32.f) - mu * mu, 0.f);
            xn_s[t] = (fv - mu) * rsqrtf(var + 1e-5f) * ln_tm_g[t] + ln_tm_b[t];
        }
        // r/k/v dots on wave 0 only (intra-wave LDS ordering, no barrier):
        // lanes 0..31: r and v; lanes 32..63: k
        const int d = t & 31;
        const float4* x4 = (const float4*)xn_s;
        const float4* w1 = (const float4*)((t < 32 ? tm_r : tm_k) + d * 32);
        float a0 = 0.f, a1 = 0.f, a2 = 0.f, a3 = 0.f;
#pragma unroll
        for (int jq = 0; jq < 2; ++jq) {
            float4 w, xv;
            w = w1[jq];     xv = x4[jq];     a0 += w.x*xv.x + w.y*xv.y + w.z*xv.z + w.w*xv.w;
            w = w1[jq + 2]; xv = x4[jq + 2]; a1 += w.x*xv.x + w.y*xv.y + w.z*xv.z + w.w*xv.w;
            w = w1[jq + 4]; xv = x4[jq + 4]; a2 += w.x*xv.x + w.y*xv.y + w.z*xv.z + w.w*xv.w;
            w = w1[jq + 6]; xv = x4[jq + 6]; a3 += w.x*xv.x + w.y*xv.y + w.z*xv.z + w.w*xv.w;
        }
        const float dot1 = (a0 + a1) + (a2 + a3);
        if (t < 32) {
            r_out[gidx + d] = sigf(dot1);
            const float4* w2 = (const float4*)(tm_v + d * 32);
            float b0 = 0.f, b1 = 0.f, b2 = 0.f, b3 = 0.f;
#pragma unroll
            for (int jq = 0; jq < 2; ++jq) {
                float4 w, xv;
                w = w2[jq];     xv = x4[jq];     b0 += w.x*xv.x + w.y*xv.y + w.z*xv.z + w.w*xv.w;
                w = w2[jq + 2]; xv = x4[jq + 2]; b1 += w.x*xv.x + w.y*xv.y + w.z*xv.z + w.w*xv.w;
                w = w2[jq + 4]; xv = x4[jq + 4]; b2 += w.x*xv.x + w.y*xv.y + w.z*xv.z + w.w*xv.w;
                w = w2[jq + 6]; xv = x4[jq + 6]; b3 += w.x*xv.x + w.y*xv.y + w.z*xv.z + w.w*xv.w;
            }
            kv_out[2 * (gidx + d) + 1] = (b0 + b1) + (b2 + b3);   // v
        } else {
            kv_out[2 * (gidx + d)] = dot1;                        // k
        }
    }
}

// ---------------------------------------------------------------------------
// k_wkv: one channel per lane; all 32 layers' (k,v) preloaded into registers
// so the 32 L2-latency loads overlap in one burst; then the serial chain.
// ---------------------------------------------------------------------------
__global__ __launch_bounds__(64) void k_wkv(
    const float* __restrict__ kv_in,
    const float* __restrict__ time_decay, const float* __restrict__ time_first,
    float* __restrict__ wkv_out)
{
    const int ch = blockIdx.x * 64 + threadIdx.x;   // (bb*32+hp)*32+d, 4096 total
    const int d = ch & 31;
    const float tf = time_first[d];
    const float wd = __expf(time_decay[d]);
    const float2* kv2 = (const float2*)kv_in;
    float2 kv[32];
#pragma unroll
    for (int l = 0; l < 32; ++l) kv[l] = kv2[l * 4096 + ch];
    float aa = 0.f, bbs = 0.f, pp = -1e30f;
#pragma unroll
    for (int l = 0; l < 32; ++l) {
        const float kc = kv[l].x, vc = kv[l].y;
        const float ww = tf + kc;
        const float p = fmaxf(pp, ww);
        const float e1 = __expf(pp - p), e2 = __expf(ww - p);
        wkv_out[l * 4096 + ch] = (e1 * aa + e2 * vc) / fmaxf(e1 * bbs + e2, 1e-8f);
        const float ww2 = pp - wd;
        const float p2 = fmaxf(ww2, kc);
        const float e1b = __expf(ww2 - p2), e2b = __expf(kc - p2);
        aa = e1b * aa + e2b * vc;
        bbs = e1b * bbs + e2b;
        pp = p2;
    }
}

// ---------------------------------------------------------------------------
// k_merge: wave-0-only front-end (LDS scratch, intra-wave ordering only),
// ONE __syncthreads, then mask+merge stream (x loaded in-stream to keep VGPR
// low -> high occupancy); per-block partial sums stored contention-free.
// ---------------------------------------------------------------------------
__global__ __launch_bounds__(256, 4) void k_merge(
    const float* __restrict__ x,
    const float* __restrict__ f_in, const float* __restrict__ r_in,
    const float* __restrict__ wkv_in,
    const float* __restrict__ tm_out,
    const float* __restrict__ ln_cm_g, const float* __restrict__ ln_cm_b,
    const float* __restrict__ cm_k, const float* __restrict__ cm_v,
    const float* __restrict__ cm_r,
    const float* __restrict__ gate_w, const float* __restrict__ gate_b,
    const float* __restrict__ row_w, const float* __restrict__ row_b,
    const float* __restrict__ col_w, const float* __restrict__ col_b,
    float* __restrict__ out, float* __restrict__ gpart, float* __restrict__ mpart)
{
    __shared__ __align__(16) float wkv_s[32];
    __shared__ __align__(16) float xn2_s[32];
    __shared__ __align__(16) float kk_s[64];
    __shared__ __align__(16) float fs[32];     // final feats (y2)
    __shared__ float row_s[64], col_s[64];
    __shared__ float gate_sh;
    __shared__ float red2[4];
    const int bid = blockIdx.x;
    const int hp = bid & 31, l = (bid >> 5) & 31, bb = bid >> 10;
    const int t = threadIdx.x;
    const int gidx = ((l * 4 + bb) * 32 + hp) * 32;

    const float4* pa = (const float4*)(x + (size_t)(bb * 2048 + l * 32 + hp) * 4096);
    const float4* pb = (const float4*)(x + (size_t)(bb * 2048 + 1024 + l * 32 + hp) * 4096);
    float4* po = (float4*)(out + (size_t)(bb * 1024 + l * 32 + hp) * 4096);

    // ---- wave-0-only front-end: no block-wide barriers in here ----
    if (t < 64) {
        float yv = 0.f, y2 = 0.f;
        if (t < 32) {
            wkv_s[t] = wkv_in[gidx + t];
            const float fv = f_in[gidx + t];
            const float rv = r_in[gidx + t];
            // y = f + r * (wkv @ tm_out[t]);  wkv via LDS (same-wave ordering)
            const float4* w4 = (const float4*)(tm_out + t * 32);
            const float4* x4 = (const float4*)wkv_s;
            float a0 = 0.f, a1 = 0.f, a2 = 0.f, a3 = 0.f;
#pragma unroll
            for (int jq = 0; jq < 2; ++jq) {
                float4 w, xv;
                w = w4[jq];     xv = x4[jq];     a0 += w.x*xv.x + w.y*xv.y + w.z*xv.z + w.w*xv.w;
                w = w4[jq + 2]; xv = x4[jq + 2]; a1 += w.x*xv.x + w.y*xv.y + w.z*xv.z + w.w*xv.w;
                w = w4[jq + 4]; xv = x4[jq + 4]; a2 += w.x*xv.x + w.y*xv.y + w.z*xv.z + w.w*xv.w;
                w = w4[jq + 6]; xv = x4[jq + 6]; a3 += w.x*xv.x + w.y*xv.y + w.z*xv.z + w.w*xv.w;
            }
            yv = fv + rv * ((a0 + a1) + (a2 + a3));
            // LN2 across lanes 0..31
            float s = yv, q = yv * yv;
#pragma unroll
            for (int m = 1; m < 32; m <<= 1) { s += __shfl_xor(s, m, 32); q += __shfl_xor(q, m, 32); }
            const float mu = s * (1.f / 32.f);
            const float var = fmaxf(q * (1.f / 32.f) - mu * mu, 0.f);
            xn2_s[t] = (yv - mu) * rsqrtf(var + 1e-5f) * ln_cm_g[t] + ln_cm_b[t];
        }
        {   // kk[e] = relu(xn2 @ cm_k[e])^2  -- all 64 lanes
            const float4* w4 = (const float4*)(cm_k + t * 32);
            const float4* x4 = (const float4*)xn2_s;
            float a0 = 0.f, a1 = 0.f, a2 = 0.f, a3 = 0.f;
#pragma unroll
            for (int jq = 0; jq < 2; ++jq) {
                float4 w, xv;
                w = w4[jq];     xv = x4[jq];     a0 += w.x*xv.x + w.y*xv.y + w.z*xv.z + w.w*xv.w;
                w = w4[jq + 2]; xv = x4[jq + 2]; a1 += w.x*xv.x + w.y*xv.y + w.z*xv.z + w.w*xv.w;
                w = w4[jq + 4]; xv = x4[jq + 4]; a2 += w.x*xv.x + w.y*xv.y + w.z*xv.z + w.w*xv.w;
                w = w4[jq + 6]; xv = x4[jq + 6]; a3 += w.x*xv.x + w.y*xv.y + w.z*xv.z + w.w*xv.w;
            }
            float kk = fmaxf((a0 + a1) + (a2 + a3), 0.f);
            kk_s[t] = kk * kk;
        }
        if (t < 32) {
            // cr[d] = sigmoid(xn2 @ cm_r[d])
            float cr;
            {
                const float4* w4 = (const float4*)(cm_r + t * 32);
                const float4* x4 = (const float4*)xn2_s;
                float a0 = 0.f, a1 = 0.f, a2 = 0.f, a3 = 0.f;
#pragma unroll
                for (int jq = 0; jq < 2; ++jq) {
                    float4 w, xv;
                    w = w4[jq];     xv = x4[jq];     a0 += w.x*xv.x + w.y*xv.y + w.z*xv.z + w.w*xv.w;
                    w = w4[jq + 2]; xv = x4[jq + 2]; a1 += w.x*xv.x + w.y*xv.y + w.z*xv.z + w.w*xv.w;
                    w = w4[jq + 4]; xv = x4[jq + 4]; a2 += w.x*xv.x + w.y*xv.y + w.z*xv.z + w.w*xv.w;
                    w = w4[jq + 6]; xv = x4[jq + 6]; a3 += w.x*xv.x + w.y*xv.y + w.z*xv.z + w.w*xv.w;
                }
                cr = sigf((a0 + a1) + (a2 + a3));
            }
            // y2 = y + cr * (kk @ cm_v[t])
            {
                const float4* w4 = (const float4*)(cm_v + t * 64);
                const float4* x4 = (const float4*)kk_s;
                float a0 = 0.f, a1 = 0.f, a2 = 0.f, a3 = 0.f;
#pragma unroll
                for (int jq = 0; jq < 4; ++jq) {
                    float4 w, xv;
                    w = w4[jq];      xv = x4[jq];      a0 += w.x*xv.x + w.y*xv.y + w.z*xv.z + w.w*xv.w;
                    w = w4[jq + 4];  xv = x4[jq + 4];  a1 += w.x*xv.x + w.y*xv.y + w.z*xv.z + w.w*xv.w;
                    w = w4[jq + 8];  xv = x4[jq + 8];  a2 += w.x*xv.x + w.y*xv.y + w.z*xv.z + w.w*xv.w;
                    w = w4[jq + 12]; xv = x4[jq + 12]; a3 += w.x*xv.x + w.y*xv.y + w.z*xv.z + w.w*xv.w;
                }
                y2 = yv + cr * ((a0 + a1) + (a2 + a3));
            }
            fs[t] = y2;
            // gate = fs . gate_w + gate_b via shuffle reduce (width 32)
            float g = y2 * gate_w[t];
#pragma unroll
            for (int m = 1; m < 32; m <<= 1) g += __shfl_xor(g, m, 32);
            if (t == 0) gate_sh = g + gate_b[0];
        }
        {   // row_s[t] and col_s[t] from fs (all 64 lanes)
            float a0 = row_b[t], a1 = 0.f, a2 = 0.f, a3 = 0.f;
            float c0 = col_b[t], c1 = 0.f, c2 = 0.f, c3 = 0.f;
#pragma unroll
            for (int d2 = 0; d2 < 8; ++d2) {
                const float f0 = fs[d2], f1 = fs[d2 + 8], f2 = fs[d2 + 16], f3 = fs[d2 + 24];
                a0 += f0 * row_w[t * 32 + d2];
                a1 += f1 * row_w[t * 32 + d2 + 8];
                a2 += f2 * row_w[t * 32 + d2 + 16];
                a3 += f3 * row_w[t * 32 + d2 + 24];
                c0 += f0 * col_w[t * 32 + d2];
                c1 += f1 * col_w[t * 32 + d2 + 8];
                c2 += f2 * col_w[t * 32 + d2 + 16];
                c3 += f3 * col_w[t * 32 + d2 + 24];
            }
            row_s[t] = (a0 + a1) + (a2 + a3);
            col_s[t] = (c0 + c1) + (c2 + c3);
        }
    }
    __syncthreads();   // the ONLY pre-stream barrier

    const float gate = gate_sh;
    float msum = 0.f;
#pragma unroll
    for (int it = 0; it < 4; ++it) {
        const int i = t + it * 256;
        const float4 a4 = pa[i];
        const float4 b4 = pb[i];
        const int h = i >> 4, w0 = (i & 15) * 4;
        const float gr = gate + row_s[h];
        const float m0 = sigf(gr + col_s[w0 + 0]);
        const float m1 = sigf(gr + col_s[w0 + 1]);
        const float m2 = sigf(gr + col_s[w0 + 2]);
        const float m3 = sigf(gr + col_s[w0 + 3]);
        float4 o;
        o.x = b4.x + m0 * (a4.x - b4.x);
        o.y = b4.y + m1 * (a4.y - b4.y);
        o.z = b4.z + m2 * (a4.z - b4.z);
        o.w = b4.w + m3 * (a4.w - b4.w);
        po[i] = o;
        msum += m0 + m1 + m2 + m3;
    }
#pragma unroll
    for (int m = 1; m < 64; m <<= 1) msum += __shfl_xor(msum, m);
    if ((t & 63) == 0) red2[t >> 6] = msum;
    __syncthreads();
    if (t == 0) {
        mpart[bid] = red2[0] + red2[1] + red2[2] + red2[3];
        gpart[bid] = sigf(gate);
    }
}

// ---------------------------------------------------------------------------
// k_final: reduce 4096 per-block partials into the two scalar outputs.
// ---------------------------------------------------------------------------
__global__ __launch_bounds__(256) void k_final(
    const float* __restrict__ gpart, const float* __restrict__ mpart,
    float* __restrict__ out)
{
    __shared__ float rg[4], rm[4];
    const int t = threadIdx.x;
    float gs = 0.f, ms = 0.f;
    for (int i = t; i < 4096; i += 256) { gs += gpart[i]; ms += mpart[i]; }
#pragma unroll
    for (int m = 1; m < 64; m <<= 1) { gs += __shfl_xor(gs, m); ms += __shfl_xor(ms, m); }
    if ((t & 63) == 0) { rg[t >> 6] = gs; rm[t >> 6] = ms; }
    __syncthreads();
    if (t == 0) {
        out[16777216] = (rg[0] + rg[1] + rg[2] + rg[3]) * (1.f / 4096.f);
        out[16777217] = (rm[0] + rm[1] + rm[2] + rm[3]) * (1.f / 16777216.f);
    }
}

extern "C" void kernel_launch(void* const* d_in, const int* in_sizes, int n_in,
                              void* d_out, int out_size, void* d_ws, size_t ws_size,
                              hipStream_t stream) {
    const float* x          = (const float*)d_in[0];
    const float* in_proj_w  = (const float*)d_in[1];
    const float* in_proj_b  = (const float*)d_in[2];
    const float* layer_emb  = (const float*)d_in[3];
    const float* time_decay = (const float*)d_in[4];
    const float* time_first = (const float*)d_in[5];
    const float* ln_tm_g    = (const float*)d_in[6];
    const float* ln_tm_b    = (const float*)d_in[7];
    const float* tm_r       = (const float*)d_in[8];
    const float* tm_k       = (const float*)d_in[9];
    const float* tm_v       = (const float*)d_in[10];
    const float* tm_out     = (const float*)d_in[11];
    const float* ln_cm_g    = (const float*)d_in[12];
    const float* ln_cm_b    = (const float*)d_in[13];
    const float* cm_k       = (const float*)d_in[14];
    const float* cm_v       = (const float*)d_in[15];
    const float* cm_r       = (const float*)d_in[16];
    const float* gate_w     = (const float*)d_in[17];
    const float* gate_b     = (const float*)d_in[18];
    const float* row_w      = (const float*)d_in[19];
    const float* row_b      = (const float*)d_in[20];
    const float* col_w      = (const float*)d_in[21];
    const float* col_b      = (const float*)d_in[22];
    float* out = (float*)d_out;

    float* wsf    = (float*)d_ws;
    float* f_ws   = wsf;               // 131072  [l][b][hp][d]
    float* r_ws   = wsf + 131072;      // 131072
    float* kv_ws  = wsf + 262144;      // 262144  [l][b][hp][d] x {k,v} packed
    float* wkv_ws = wsf + 524288;      // 131072
    float* gpart  = wsf + 655360;      // 4096
    float* mpart  = wsf + 659456;      // 4096

    k_stats<<<dim3(4096), dim3(256), 0, stream>>>(
        x, in_proj_w, in_proj_b, layer_emb, ln_tm_g, ln_tm_b,
        tm_r, tm_k, tm_v, f_ws, r_ws, kv_ws);
    k_wkv<<<dim3(64), dim3(64), 0, stream>>>(
        kv_ws, time_decay, time_first, wkv_ws);
    k_merge<<<dim3(4096), dim3(256), 0, stream>>>(
        x, f_ws, r_ws, wkv_ws, tm_out, ln_cm_g, ln_cm_b, cm_k, cm_v, cm_r,
        gate_w, gate_b, row_w, row_b, col_w, col_b, out, gpart, mpart);
    k_final<<<dim3(1), dim3(256), 0, stream>>>(gpart, mpart, out);
}

// Round 8
// 299.099 us; speedup vs baseline: 1.2691x; 1.0059x over previous
//
#include <hip/hip_runtime.h>
#include <math.h>

// B=4, L=32, HP=32, H=64, W=64, D=32, DFFN=64
// 3-kernel structure:
//   k_stats: stats + in_proj + LN1 + r/k/v projections; 1 barrier, wave-0 tail
//   k_fused: in-block WKV recompute (32 kv float2 reg-preloaded, statically
//            indexed unrolled chain) + wave-0 front-end + merge stream +
//            per-block partials.  [R3 exonerated the recompute: R2/R3 both
//            133us with/without it -- the cost was the same-address atomics.]
//   k_final: reduce 4096 partials -> 2 scalars [1 block]
// NO same-address atomics (R2/R3: ~133us cross-XCD floor). NO nontemporal
// stores (R1/R5 container failures). NO cooperative launch (R7: silently
// failed -> zero output; absmax == max|ref|).
// ws layout (floats): f 131072 | r 131072 | kv 262144 | gpart 4096 | mpart 4096

__device__ __forceinline__ float sigf(float v) { return 1.0f / (1.0f + __expf(-v)); }

// ---------------------------------------------------------------------------
// k_stats: per-(b,l,hp) stats over a/b, in_proj -> feat, then LN1 + r/k/v.
// One __syncthreads total; all post-reduce work on wave 0.
// ---------------------------------------------------------------------------
__global__ __launch_bounds__(256, 4) void k_stats(
    const float* __restrict__ x, const float* __restrict__ in_proj_w,
    const float* __restrict__ in_proj_b, const float* __restrict__ layer_emb,
    const float* __restrict__ ln_tm_g, const float* __restrict__ ln_tm_b,
    const float* __restrict__ tm_r, const float* __restrict__ tm_k,
    const float* __restrict__ tm_v,
    float* __restrict__ f_out, float* __restrict__ r_out,
    float* __restrict__ kv_out)
{
    __shared__ float red[4][9];
    __shared__ __align__(16) float xn_s[32];
    const int bid = blockIdx.x;
    const int hp = bid & 31, l = (bid >> 5) & 31, bb = bid >> 10;
    const float4* pa = (const float4*)(x + (size_t)(bb * 2048 + l * 32 + hp) * 4096);
    const float4* pb = (const float4*)(x + (size_t)(bb * 2048 + 1024 + l * 32 + hp) * 4096);
    const int t = threadIdx.x;
    const int gidx = ((l * 4 + bb) * 32 + hp) * 32;

    float sa = 0.f, saa = 0.f, sb = 0.f, sbb = 0.f, sab = 0.f;
    float mna = 3.4e38f, mxa = -3.4e38f, mnb = 3.4e38f, mxb = -3.4e38f;
#pragma unroll
    for (int it = 0; it < 4; ++it) {
        float4 a4 = pa[t + it * 256];
        float4 b4 = pb[t + it * 256];
        sa  += a4.x + a4.y + a4.z + a4.w;
        sb  += b4.x + b4.y + b4.z + b4.w;
        saa += a4.x * a4.x + a4.y * a4.y + a4.z * a4.z + a4.w * a4.w;
        sbb += b4.x * b4.x + b4.y * b4.y + b4.z * b4.z + b4.w * b4.w;
        sab += a4.x * b4.x + a4.y * b4.y + a4.z * b4.z + a4.w * b4.w;
        mna = fminf(mna, fminf(fminf(a4.x, a4.y), fminf(a4.z, a4.w)));
        mxa = fmaxf(mxa, fmaxf(fmaxf(a4.x, a4.y), fmaxf(a4.z, a4.w)));
        mnb = fminf(mnb, fminf(fminf(b4.x, b4.y), fminf(b4.z, b4.w)));
        mxb = fmaxf(mxb, fmaxf(fmaxf(b4.x, b4.y), fmaxf(b4.z, b4.w)));
    }
#pragma unroll
    for (int m = 1; m < 64; m <<= 1) {
        sa  += __shfl_xor(sa, m);
        saa += __shfl_xor(saa, m);
        sb  += __shfl_xor(sb, m);
        sbb += __shfl_xor(sbb, m);
        sab += __shfl_xor(sab, m);
        mna = fminf(mna, __shfl_xor(mna, m));
        mxa = fmaxf(mxa, __shfl_xor(mxa, m));
        mnb = fminf(mnb, __shfl_xor(mnb, m));
        mxb = fmaxf(mxb, __shfl_xor(mxb, m));
    }
    const int lane = t & 63, wv = t >> 6;
    if (lane == 0) {
        red[wv][0] = sa;  red[wv][1] = saa; red[wv][2] = sb;  red[wv][3] = sbb;
        red[wv][4] = sab; red[wv][5] = mna; red[wv][6] = mxa; red[wv][7] = mnb;
        red[wv][8] = mxb;
    }
    __syncthreads();   // the ONLY barrier
    if (t < 64) {
        if (t < 32) {
            const float SA  = red[0][0] + red[1][0] + red[2][0] + red[3][0];
            const float SAA = red[0][1] + red[1][1] + red[2][1] + red[3][1];
            const float SB  = red[0][2] + red[1][2] + red[2][2] + red[3][2];
            const float SBB = red[0][3] + red[1][3] + red[2][3] + red[3][3];
            const float SAB = red[0][4] + red[1][4] + red[2][4] + red[3][4];
            const float MNA = fminf(fminf(red[0][5], red[1][5]), fminf(red[2][5], red[3][5]));
            const float MXA = fmaxf(fmaxf(red[0][6], red[1][6]), fmaxf(red[2][6], red[3][6]));
            const float MNB = fminf(fminf(red[0][7], red[1][7]), fminf(red[2][7], red[3][7]));
            const float MXB = fmaxf(fmaxf(red[0][8], red[1][8]), fmaxf(red[2][8], red[3][8]));
            const float inv_n = 1.f / 4096.f, inv_nm1 = 1.f / 4095.f;
            float st[12];
            st[0] = SA * inv_n;
            st[1] = sqrtf(fmaxf(SAA - SA * SA * inv_n, 0.f) * inv_nm1);
            st[2] = MNA; st[3] = MXA;
            st[4] = SB * inv_n;
            st[5] = sqrtf(fmaxf(SBB - SB * SB * inv_n, 0.f) * inv_nm1);
            st[6] = MNB; st[7] = MXB;
            const float SD = SA - SB, SDD = SAA - 2.f * SAB + SBB;
            st[8]  = SD * inv_n;
            st[9]  = sqrtf(fmaxf(SDD - SD * SD * inv_n, 0.f) * inv_nm1);
            st[10] = sqrtf(fmaxf(SDD, 0.f));
            const float na = fmaxf(sqrtf(SAA), 1e-8f), nb2 = fmaxf(sqrtf(SBB), 1e-8f);
            st[11] = SAB / (na * nb2);
            float fv = in_proj_b[t] + layer_emb[l * 32 + t];
#pragma unroll
            for (int s2 = 0; s2 < 12; ++s2) fv += st[s2] * in_proj_w[t * 12 + s2];
            f_out[gidx + t] = fv;
            float s = fv, q = fv * fv;
#pragma unroll
            for (int m = 1; m < 32; m <<= 1) { s += __shfl_xor(s, m, 32); q += __shfl_xor(q, m, 32); }
            const float mu = s * (1.f / 32.f);
            const float var = fmaxf(q * (1.f / 32.f) - mu * mu, 0.f);
            xn_s[t] = (fv - mu) * rsqrtf(var + 1e-5f) * ln_tm_g[t] + ln_tm_b[t];
        }
        // r/k/v dots on wave 0 only: lanes 0..31: r and v; lanes 32..63: k
        const int d = t & 31;
        const float4* x4 = (const float4*)xn_s;
        const float4* w1 = (const float4*)((t < 32 ? tm_r : tm_k) + d * 32);
        float a0 = 0.f, a1 = 0.f, a2 = 0.f, a3 = 0.f;
#pragma unroll
        for (int jq = 0; jq < 2; ++jq) {
            float4 w, xv;
            w = w1[jq];     xv = x4[jq];     a0 += w.x*xv.x + w.y*xv.y + w.z*xv.z + w.w*xv.w;
            w = w1[jq + 2]; xv = x4[jq + 2]; a1 += w.x*xv.x + w.y*xv.y + w.z*xv.z + w.w*xv.w;
            w = w1[jq + 4]; xv = x4[jq + 4]; a2 += w.x*xv.x + w.y*xv.y + w.z*xv.z + w.w*xv.w;
            w = w1[jq + 6]; xv = x4[jq + 6]; a3 += w.x*xv.x + w.y*xv.y + w.z*xv.z + w.w*xv.w;
        }
        const float dot1 = (a0 + a1) + (a2 + a3);
        if (t < 32) {
            r_out[gidx + d] = sigf(dot1);
            const float4* w2 = (const float4*)(tm_v + d * 32);
            float b0 = 0.f, b1 = 0.f, b2 = 0.f, b3 = 0.f;
#pragma unroll
            for (int jq = 0; jq < 2; ++jq) {
                float4 w, xv;
                w = w2[jq];     xv = x4[jq];     b0 += w.x*xv.x + w.y*xv.y + w.z*xv.z + w.w*xv.w;
                w = w2[jq + 2]; xv = x4[jq + 2]; b1 += w.x*xv.x + w.y*xv.y + w.z*xv.z + w.w*xv.w;
                w = w2[jq + 4]; xv = x4[jq + 4]; b2 += w.x*xv.x + w.y*xv.y + w.z*xv.z + w.w*xv.w;
                w = w2[jq + 6]; xv = x4[jq + 6]; b3 += w.x*xv.x + w.y*xv.y + w.z*xv.z + w.w*xv.w;
            }
            kv_out[2 * (gidx + d) + 1] = (b0 + b1) + (b2 + b3);   // v
        } else {
            kv_out[2 * (gidx + d)] = dot1;                        // k
        }
    }
}

// ---------------------------------------------------------------------------
// k_fused: in-block WKV recompute (reg-preloaded) + wave-0 front-end (LDS
// scratch, intra-wave ordering only), ONE pre-stream barrier, merge stream,
// per-block partial stores (contention-free).
// ---------------------------------------------------------------------------
__global__ __launch_bounds__(256, 4) void k_fused(
    const float* __restrict__ x,
    const float* __restrict__ f_in, const float* __restrict__ r_in,
    const float* __restrict__ kv_in,
    const float* __restrict__ time_decay, const float* __restrict__ time_first,
    const float* __restrict__ tm_out,
    const float* __restrict__ ln_cm_g, const float* __restrict__ ln_cm_b,
    const float* __restrict__ cm_k, const float* __restrict__ cm_v,
    const float* __restrict__ cm_r,
    const float* __restrict__ gate_w, const float* __restrict__ gate_b,
    const float* __restrict__ row_w, const float* __restrict__ row_b,
    const float* __restrict__ col_w, const float* __restrict__ col_b,
    float* __restrict__ out, float* __restrict__ gpart, float* __restrict__ mpart)
{
    __shared__ __align__(16) float wkv_s[32];
    __shared__ __align__(16) float xn2_s[32];
    __shared__ __align__(16) float kk_s[64];
    __shared__ __align__(16) float fs[32];
    __shared__ float row_s[64], col_s[64];
    __shared__ float gate_sh;
    __shared__ float red2[4];
    const int bid = blockIdx.x;
    const int hp = bid & 31, l = (bid >> 5) & 31, bb = bid >> 10;
    const int t = threadIdx.x;
    const int chb = bb * 1024 + hp * 32;       // channel base (layer stride 4096)
    const int gidx = l * 4096 + chb;

    const float4* pa = (const float4*)(x + (size_t)(bb * 2048 + l * 32 + hp) * 4096);
    const float4* pb = (const float4*)(x + (size_t)(bb * 2048 + 1024 + l * 32 + hp) * 4096);
    float4* po = (float4*)(out + (size_t)(bb * 1024 + l * 32 + hp) * 4096);

    // ---- wave-0-only front-end: no block-wide barriers in here ----
    if (t < 64) {
        float yv = 0.f, y2 = 0.f;
        if (t < 32) {
            // ---- WKV recompute for channel (bb,hp,t), layers 0..l ----
            // All 32 (k,v) loaded in one burst (static indices -> registers,
            // rule #20); chain fully unrolled, predicated on block-uniform l.
            const float2* kv2p = (const float2*)kv_in;
            float2 kv[32];
#pragma unroll
            for (int l2 = 0; l2 < 32; ++l2) kv[l2] = kv2p[l2 * 4096 + chb + t];
            const float tf = time_first[t];
            const float wd = __expf(time_decay[t]);
            float aa = 0.f, bbs = 0.f, pp = -1e30f, wkv = 0.f;
#pragma unroll
            for (int l2 = 0; l2 < 32; ++l2) {
                if (l2 < l) {          // state-only update
                    const float ww2 = pp - wd;
                    const float p2 = fmaxf(ww2, kv[l2].x);
                    const float e1b = __expf(ww2 - p2), e2b = __expf(kv[l2].x - p2);
                    aa = e1b * aa + e2b * kv[l2].y;
                    bbs = e1b * bbs + e2b;
                    pp = p2;
                } else if (l2 == l) {  // emit wkv from pre-update state
                    const float ww = tf + kv[l2].x;
                    const float p = fmaxf(pp, ww);
                    const float e1 = __expf(pp - p), e2 = __expf(ww - p);
                    wkv = (e1 * aa + e2 * kv[l2].y) / fmaxf(e1 * bbs + e2, 1e-8f);
                }
            }
            wkv_s[t] = wkv;
            const float fv = f_in[gidx + t];
            const float rv = r_in[gidx + t];
            // y = f + r * (wkv @ tm_out[t]);  wkv via LDS (same-wave ordering)
            const float4* w4 = (const float4*)(tm_out + t * 32);
            const float4* x4 = (const float4*)wkv_s;
            float a0 = 0.f, a1 = 0.f, a2 = 0.f, a3 = 0.f;
#pragma unroll
            for (int jq = 0; jq < 2; ++jq) {
                float4 w, xv;
                w = w4[jq];     xv = x4[jq];     a0 += w.x*xv.x + w.y*xv.y + w.z*xv.z + w.w*xv.w;
                w = w4[jq + 2]; xv = x4[jq + 2]; a1 += w.x*xv.x + w.y*xv.y + w.z*xv.z + w.w*xv.w;
                w = w4[jq + 4]; xv = x4[jq + 4]; a2 += w.x*xv.x + w.y*xv.y + w.z*xv.z + w.w*xv.w;
                w = w4[jq + 6]; xv = x4[jq + 6]; a3 += w.x*xv.x + w.y*xv.y + w.z*xv.z + w.w*xv.w;
            }
            yv = fv + rv * ((a0 + a1) + (a2 + a3));
            // LN2 across lanes 0..31
            float s = yv, q = yv * yv;
#pragma unroll
            for (int m = 1; m < 32; m <<= 1) { s += __shfl_xor(s, m, 32); q += __shfl_xor(q, m, 32); }
            const float mu = s * (1.f / 32.f);
            const float var = fmaxf(q * (1.f / 32.f) - mu * mu, 0.f);
            xn2_s[t] = (yv - mu) * rsqrtf(var + 1e-5f) * ln_cm_g[t] + ln_cm_b[t];
        }
        {   // kk[e] = relu(xn2 @ cm_k[e])^2  -- all 64 lanes
            const float4* w4 = (const float4*)(cm_k + t * 32);
            const float4* x4 = (const float4*)xn2_s;
            float a0 = 0.f, a1 = 0.f, a2 = 0.f, a3 = 0.f;
#pragma unroll
            for (int jq = 0; jq < 2; ++jq) {
                float4 w, xv;
                w = w4[jq];     xv = x4[jq];     a0 += w.x*xv.x + w.y*xv.y + w.z*xv.z + w.w*xv.w;
                w = w4[jq + 2]; xv = x4[jq + 2]; a1 += w.x*xv.x + w.y*xv.y + w.z*xv.z + w.w*xv.w;
                w = w4[jq + 4]; xv = x4[jq + 4]; a2 += w.x*xv.x + w.y*xv.y + w.z*xv.z + w.w*xv.w;
                w = w4[jq + 6]; xv = x4[jq + 6]; a3 += w.x*xv.x + w.y*xv.y + w.z*xv.z + w.w*xv.w;
            }
            float kk = fmaxf((a0 + a1) + (a2 + a3), 0.f);
            kk_s[t] = kk * kk;
        }
        if (t < 32) {
            float cr;
            {   // cr[d] = sigmoid(xn2 @ cm_r[d])
                const float4* w4 = (const float4*)(cm_r + t * 32);
                const float4* x4 = (const float4*)xn2_s;
                float a0 = 0.f, a1 = 0.f, a2 = 0.f, a3 = 0.f;
#pragma unroll
                for (int jq = 0; jq < 2; ++jq) {
                    float4 w, xv;
                    w = w4[jq];     xv = x4[jq];     a0 += w.x*xv.x + w.y*xv.y + w.z*xv.z + w.w*xv.w;
                    w = w4[jq + 2]; xv = x4[jq + 2]; a1 += w.x*xv.x + w.y*xv.y + w.z*xv.z + w.w*xv.w;
                    w = w4[jq + 4]; xv = x4[jq + 4]; a2 += w.x*xv.x + w.y*xv.y + w.z*xv.z + w.w*xv.w;
                    w = w4[jq + 6]; xv = x4[jq + 6]; a3 += w.x*xv.x + w.y*xv.y + w.z*xv.z + w.w*xv.w;
                }
                cr = sigf((a0 + a1) + (a2 + a3));
            }
            {   // y2 = y + cr * (kk @ cm_v[t])
                const float4* w4 = (const float4*)(cm_v + t * 64);
                const float4* x4 = (const float4*)kk_s;
                float a0 = 0.f, a1 = 0.f, a2 = 0.f, a3 = 0.f;
#pragma unroll
                for (int jq = 0; jq < 4; ++jq) {
                    float4 w, xv;
                    w = w4[jq];      xv = x4[jq];      a0 += w.x*xv.x + w.y*xv.y + w.z*xv.z + w.w*xv.w;
                    w = w4[jq + 4];  xv = x4[jq + 4];  a1 += w.x*xv.x + w.y*xv.y + w.z*xv.z + w.w*xv.w;
                    w = w4[jq + 8];  xv = x4[jq + 8];  a2 += w.x*xv.x + w.y*xv.y + w.z*xv.z + w.w*xv.w;
                    w = w4[jq + 12]; xv = x4[jq + 12]; a3 += w.x*xv.x + w.y*xv.y + w.z*xv.z + w.w*xv.w;
                }
                y2 = yv + cr * ((a0 + a1) + (a2 + a3));
            }
            fs[t] = y2;
            // gate = fs . gate_w + gate_b via shuffle reduce (width 32)
            float g = y2 * gate_w[t];
#pragma unroll
            for (int m = 1; m < 32; m <<= 1) g += __shfl_xor(g, m, 32);
            if (t == 0) gate_sh = g + gate_b[0];
        }
        {   // row_s[t] and col_s[t] from fs (all 64 lanes)
            float a0 = row_b[t], a1 = 0.f, a2 = 0.f, a3 = 0.f;
            float c0 = col_b[t], c1 = 0.f, c2 = 0.f, c3 = 0.f;
#pragma unroll
            for (int d2 = 0; d2 < 8; ++d2) {
                const float f0 = fs[d2], f1 = fs[d2 + 8], f2 = fs[d2 + 16], f3 = fs[d2 + 24];
                a0 += f0 * row_w[t * 32 + d2];
                a1 += f1 * row_w[t * 32 + d2 + 8];
                a2 += f2 * row_w[t * 32 + d2 + 16];
                a3 += f3 * row_w[t * 32 + d2 + 24];
                c0 += f0 * col_w[t * 32 + d2];
                c1 += f1 * col_w[t * 32 + d2 + 8];
                c2 += f2 * col_w[t * 32 + d2 + 16];
                c3 += f3 * col_w[t * 32 + d2 + 24];
            }
            row_s[t] = (a0 + a1) + (a2 + a3);
            col_s[t] = (c0 + c1) + (c2 + c3);
        }
    }
    __syncthreads();   // the ONLY pre-stream barrier

    const float gate = gate_sh;
    float msum = 0.f;
#pragma unroll
    for (int it = 0; it < 4; ++it) {
        const int i = t + it * 256;
        const float4 a4 = pa[i];
        const float4 b4 = pb[i];
        const int h = i >> 4, w0 = (i & 15) * 4;
        const float gr = gate + row_s[h];
        const float m0 = sigf(gr + col_s[w0 + 0]);
        const float m1 = sigf(gr + col_s[w0 + 1]);
        const float m2 = sigf(gr + col_s[w0 + 2]);
        const float m3 = sigf(gr + col_s[w0 + 3]);
        float4 o;
        o.x = b4.x + m0 * (a4.x - b4.x);
        o.y = b4.y + m1 * (a4.y - b4.y);
        o.z = b4.z + m2 * (a4.z - b4.z);
        o.w = b4.w + m3 * (a4.w - b4.w);
        po[i] = o;
        msum += m0 + m1 + m2 + m3;
    }
#pragma unroll
    for (int m = 1; m < 64; m <<= 1) msum += __shfl_xor(msum, m);
    if ((t & 63) == 0) red2[t >> 6] = msum;
    __syncthreads();
    if (t == 0) {
        mpart[bid] = red2[0] + red2[1] + red2[2] + red2[3];
        gpart[bid] = sigf(gate);
    }
}

// ---------------------------------------------------------------------------
// k_final: reduce 4096 per-block partials into the two scalar outputs.
// ---------------------------------------------------------------------------
__global__ __launch_bounds__(256) void k_final(
    const float* __restrict__ gpart, const float* __restrict__ mpart,
    float* __restrict__ out)
{
    __shared__ float rg[4], rm[4];
    const int t = threadIdx.x;
    float gs = 0.f, ms = 0.f;
    for (int i = t; i < 4096; i += 256) { gs += gpart[i]; ms += mpart[i]; }
#pragma unroll
    for (int m = 1; m < 64; m <<= 1) { gs += __shfl_xor(gs, m); ms += __shfl_xor(ms, m); }
    if ((t & 63) == 0) { rg[t >> 6] = gs; rm[t >> 6] = ms; }
    __syncthreads();
    if (t == 0) {
        out[16777216] = (rg[0] + rg[1] + rg[2] + rg[3]) * (1.f / 4096.f);
        out[16777217] = (rm[0] + rm[1] + rm[2] + rm[3]) * (1.f / 16777216.f);
    }
}

extern "C" void kernel_launch(void* const* d_in, const int* in_sizes, int n_in,
                              void* d_out, int out_size, void* d_ws, size_t ws_size,
                              hipStream_t stream) {
    const float* x          = (const float*)d_in[0];
    const float* in_proj_w  = (const float*)d_in[1];
    const float* in_proj_b  = (const float*)d_in[2];
    const float* layer_emb  = (const float*)d_in[3];
    const float* time_decay = (const float*)d_in[4];
    const float* time_first = (const float*)d_in[5];
    const float* ln_tm_g    = (const float*)d_in[6];
    const float* ln_tm_b    = (const float*)d_in[7];
    const float* tm_r       = (const float*)d_in[8];
    const float* tm_k       = (const float*)d_in[9];
    const float* tm_v       = (const float*)d_in[10];
    const float* tm_out     = (const float*)d_in[11];
    const float* ln_cm_g    = (const float*)d_in[12];
    const float* ln_cm_b    = (const float*)d_in[13];
    const float* cm_k       = (const float*)d_in[14];
    const float* cm_v       = (const float*)d_in[15];
    const float* cm_r       = (const float*)d_in[16];
    const float* gate_w     = (const float*)d_in[17];
    const float* gate_b     = (const float*)d_in[18];
    const float* row_w      = (const float*)d_in[19];
    const float* row_b      = (const float*)d_in[20];
    const float* col_w      = (const float*)d_in[21];
    const float* col_b      = (const float*)d_in[22];
    float* out = (float*)d_out;

    float* wsf    = (float*)d_ws;
    float* f_ws   = wsf;               // 131072  [l][b][hp][d]
    float* r_ws   = wsf + 131072;      // 131072
    float* kv_ws  = wsf + 262144;      // 262144  [l][b][hp][d] x {k,v} packed
    float* gpart  = wsf + 524288;      // 4096
    float* mpart  = wsf + 528384;      // 4096

    k_stats<<<dim3(4096), dim3(256), 0, stream>>>(
        x, in_proj_w, in_proj_b, layer_emb, ln_tm_g, ln_tm_b,
        tm_r, tm_k, tm_v, f_ws, r_ws, kv_ws);
    k_fused<<<dim3(4096), dim3(256), 0, stream>>>(
        x, f_ws, r_ws, kv_ws, time_decay, time_first, tm_out,
        ln_cm_g, ln_cm_b, cm_k, cm_v, cm_r,
        gate_w, gate_b, row_w, row_b, col_w, col_b, out, gpart, mpart);
    k_final<<<dim3(1), dim3(256), 0, stream>>>(gpart, mpart, out);
}